// Round 4
// baseline (471.106 us; speedup 1.0000x reference)
//
#include <hip/hip_runtime.h>
#include <math.h>

// B=1, H=32, S=2048, D=128, N_OUT=16, QMAX=7, EPS=1e-6
// Top-k indices never needed: only 16th (outlier threshold, kept exact) and
// 17th (scale) order statistics of |x| per slice.

typedef __bf16 bf16x8 __attribute__((ext_vector_type(8)));
typedef __bf16 bf16x4 __attribute__((ext_vector_type(4)));
typedef float f32x4 __attribute__((ext_vector_type(4)));

#define H 32
#define S 2048
#define D 128

// Branch-free descending top-17 insert: t[j] = med3(x, t[j-1], t[j]).
__device__ __forceinline__ void ins17(float t[17], float x) {
#pragma unroll
    for (int j = 16; j >= 1; --j) t[j] = __builtin_amdgcn_fmed3f(x, t[j - 1], t[j]);
    t[0] = fmaxf(t[0], x);
}

// ---------------------------------------------------------------------------
// Fused stats: blocks 0..255 = K partial top-17 (per (h,ch), 256-token chunk);
// blocks 256..511 = V per-row top-17 -> vtab.
// ---------------------------------------------------------------------------
__global__ __launch_bounds__(256) void stats_kernel(const float* __restrict__ K,
                                                    const float* __restrict__ V,
                                                    float* __restrict__ cand,
                                                    float2* __restrict__ vtab) {
    __shared__ float ml[128][17];
    if (blockIdx.x < 256) {
        const int h = blockIdx.x >> 3, tc = blockIdx.x & 7;
        const int ch = threadIdx.x & 127, ts = threadIdx.x >> 7;
        const float* p = K + ((size_t)h * S + tc * 256 + ts * 128) * D + ch;
        float ta[17], tb[17];
#pragma unroll
        for (int j = 0; j < 17; ++j) { ta[j] = -1.f; tb[j] = -1.f; }
#pragma unroll 8
        for (int i = 0; i < 64; ++i) {
            ins17(ta, fabsf(p[(size_t)i * D]));
            ins17(tb, fabsf(p[(size_t)(i + 64) * D]));
        }
#pragma unroll
        for (int j = 0; j < 17; ++j) ins17(ta, tb[j]);
        if (ts == 1) {
#pragma unroll
            for (int j = 0; j < 17; ++j) ml[ch][j] = ta[j];
        }
        __syncthreads();
        if (ts == 0) {
#pragma unroll
            for (int j = 0; j < 17; ++j) ins17(ta, ml[ch][j]);
            float* o = cand + ((size_t)(h * 128 + ch) * 8 + tc) * 17;
#pragma unroll
            for (int j = 0; j < 17; ++j) o[j] = ta[j];
        }
    } else {
        const int row = (blockIdx.x - 256) * 256 + threadIdx.x;   // 65536 rows
        const float4* p = (const float4*)(V + (size_t)row * D);
        float ta[17], tb[17];
#pragma unroll
        for (int j = 0; j < 17; ++j) { ta[j] = -1.f; tb[j] = -1.f; }
#pragma unroll 4
        for (int i = 0; i < 16; ++i) {
            const float4 a = p[i], b = p[i + 16];
            ins17(ta, fabsf(a.x)); ins17(ta, fabsf(a.y));
            ins17(ta, fabsf(a.z)); ins17(ta, fabsf(a.w));
            ins17(tb, fabsf(b.x)); ins17(tb, fabsf(b.y));
            ins17(tb, fabsf(b.z)); ins17(tb, fabsf(b.w));
        }
#pragma unroll
        for (int j = 0; j < 17; ++j) ins17(ta, tb[j]);
        vtab[row] = make_float2(ta[15], fmaxf(ta[16], 1e-6f) / 7.0f);
    }
}

// ---------------------------------------------------------------------------
// K stats phase 2: merge 8 partial lists (136 floats) -> thr16 + scale.
// ---------------------------------------------------------------------------
__global__ __launch_bounds__(256) void kmerge_kernel(const float* __restrict__ cand,
                                                     float2* __restrict__ ktab) {
    const int g = blockIdx.x * 256 + threadIdx.x;      // (h*128+ch), 4096 total
    const float* p = cand + (size_t)g * 136;
    float t0[17], t1[17], t2[17], t3[17];
#pragma unroll
    for (int j = 0; j < 17; ++j) { t0[j] = -1.f; t1[j] = -1.f; t2[j] = -1.f; t3[j] = -1.f; }
#pragma unroll 2
    for (int i = 0; i < 34; ++i) {
        ins17(t0, p[i]);
        ins17(t1, p[34 + i]);
        ins17(t2, p[68 + i]);
        ins17(t3, p[102 + i]);
    }
#pragma unroll
    for (int j = 0; j < 17; ++j) { ins17(t0, t1[j]); ins17(t2, t3[j]); }
#pragma unroll
    for (int j = 0; j < 17; ++j) ins17(t0, t2[j]);
    ktab[g] = make_float2(t0[15], fmaxf(t0[16], 1e-6f) / 7.0f);
}

// ---------------------------------------------------------------------------
// Fused apply: blocks 0..8191 = K fake-quant (coalesced elementwise);
// blocks 8192..9215 = V fake-quant + transpose to vT[h][d][s].
// ---------------------------------------------------------------------------
__global__ __launch_bounds__(256) void apply_kernel(const float* __restrict__ K,
                                                    const float* __restrict__ V,
                                                    const float2* __restrict__ ktab,
                                                    const float2* __restrict__ vtab,
                                                    __bf16* __restrict__ k_rec,
                                                    __bf16* __restrict__ vT) {
    __shared__ __bf16 tile[128][72];
    if (blockIdx.x < 8192) {
        const size_t base = ((size_t)blockIdx.x * 256 + threadIdx.x) * 4;
        const int h = (int)(base >> 18);            // S*D = 2^18
        const int d0 = (int)(base & (D - 1));
        const float4 x = *(const float4*)(K + base);
        const float2* tp = ktab + h * D + d0;
        float xs[4] = {x.x, x.y, x.z, x.w};
        bf16x4 o;
#pragma unroll
        for (int c = 0; c < 4; ++c) {
            const float2 tc = tp[c];
            float v;
            if (fabsf(xs[c]) >= tc.x) v = xs[c];
            else {
                float q = rintf(xs[c] / tc.y);
                q = fminf(fmaxf(q, -7.f), 7.f);
                v = q * tc.y;
            }
            o[c] = (__bf16)v;
        }
        *(bf16x4*)(k_rec + base) = o;
    } else {
        const int lin = blockIdx.x - 8192;
        const int h = lin >> 5;
        const int s0 = (lin & 31) * 64;
        const int wv = threadIdx.x >> 6;
        const int lane = threadIdx.x & 63;
#pragma unroll
        for (int g = 0; g < 2; ++g) {
            bf16x8 b0, b1;
#pragma unroll
            for (int it = 0; it < 8; ++it) {
                const int s = s0 + wv * 16 + g * 8 + it;
                const float2 tc = vtab[h * S + s];
                const float* row = V + ((size_t)h * S + s) * D;
                const float a = row[lane], b = row[lane + 64];
                float o0, o1;
                if (fabsf(a) >= tc.x) o0 = a;
                else { float q = rintf(a / tc.y); q = fminf(fmaxf(q, -7.f), 7.f); o0 = q * tc.y; }
                if (fabsf(b) >= tc.x) o1 = b;
                else { float q = rintf(b / tc.y); q = fminf(fmaxf(q, -7.f), 7.f); o1 = q * tc.y; }
                b0[it] = (__bf16)o0;
                b1[it] = (__bf16)o1;
            }
            *(bf16x8*)&tile[lane][wv * 16 + g * 8] = b0;
            *(bf16x8*)&tile[lane + 64][wv * 16 + g * 8] = b1;
        }
        __syncthreads();
        const int dRow = threadIdx.x >> 3;
        const int c3 = threadIdx.x & 7;
#pragma unroll
        for (int i = 0; i < 4; ++i) {
            const int d = dRow + 32 * i;
            bf16x8 val = *(const bf16x8*)&tile[d][c3 * 8];
            *(bf16x8*)&vT[((size_t)h * D + d) * S + s0 + c3 * 8] = val;
        }
    }
}

// ---------------------------------------------------------------------------
// Barrier-free causal flash attention, S^T formulation.
// K A-frags and V B-frags are 16B-contiguous in global (k_rec rows, vT rows):
// load them directly per-wave (L1 absorbs intra-block 4x reuse; L2 backstops).
// No __syncthreads anywhere; only per-wave P buffer in LDS.
// qblk swizzled by head so co-resident blocks on a CU have de-correlated load.
// ---------------------------------------------------------------------------
__global__ __launch_bounds__(256, 3) void attn_kernel(const float* __restrict__ Q,
                                                      const __bf16* __restrict__ k_rec,
                                                      const __bf16* __restrict__ vT,
                                                      float* __restrict__ out) {
    __shared__ __bf16 Pl[4][16][72];

    const int h = blockIdx.y;
    const int qblk = (31 - blockIdx.x + h) & 31;     // de-correlated heavy-first
    const int tid = threadIdx.x;
    const int wv = tid >> 6;
    const int lane = tid & 63;
    const int quad = lane >> 4;
    const int col = lane & 15;
    const __bf16* kb = k_rec + (size_t)h * S * D;
    const __bf16* vb = vT + (size_t)h * D * S;
    const float kscale = 0.08838834764831845f * 1.4426950408889634f;  // 1/sqrt(D)*log2e
    const int q0 = qblk * 64;

    // Q fragments (B-operand: n=col=q, k=quad*8+j), fp32->bf16 once
    bf16x8 qf[4];
    {
        const float* qbase = Q + ((size_t)h * S + q0 + wv * 16 + col) * D + quad * 8;
#pragma unroll
        for (int kk = 0; kk < 4; ++kk) {
            const float4 a = *(const float4*)(qbase + kk * 32);
            const float4 b = *(const float4*)(qbase + kk * 32 + 4);
            qf[kk] = (bf16x8){(__bf16)a.x, (__bf16)a.y, (__bf16)a.z, (__bf16)a.w,
                              (__bf16)b.x, (__bf16)b.y, (__bf16)b.z, (__bf16)b.w};
        }
    }

    // per-lane fragment base pointers
    const __bf16* kLane = kb + (size_t)col * D + quad * 8;   // + (kt*64+c*16)*D + kk*32
    const __bf16* vLane = vb + (size_t)col * S + quad * 8;   // + dt*16*S + kt*64 + ks*32

    f32x4 oacc[8];
#pragma unroll
    for (int dt = 0; dt < 8; ++dt) oacc[dt] = (f32x4){0.f, 0.f, 0.f, 0.f};
    float mrun = -INFINITY;
    float lrun = 0.f;
    const int qloc = wv * 16 + col;

    for (int kt = 0; kt <= qblk; ++kt) {
        const int kt64 = kt * 64;

        // K fragments direct from global (16B/lane, row-contiguous)
        bf16x8 kf[4][4];
#pragma unroll
        for (int c = 0; c < 4; ++c)
#pragma unroll
            for (int kk = 0; kk < 4; ++kk)
                kf[c][kk] = *(const bf16x8*)(kLane + (size_t)(kt64 + c * 16) * D + kk * 32);

        // S^T = K_tile @ Q^T
        f32x4 sacc[4];
#pragma unroll
        for (int c = 0; c < 4; ++c) sacc[c] = (f32x4){0.f, 0.f, 0.f, 0.f};
#pragma unroll
        for (int kk = 0; kk < 4; ++kk)
#pragma unroll
            for (int c = 0; c < 4; ++c)
                sacc[c] = __builtin_amdgcn_mfma_f32_16x16x32_bf16(kf[c][kk], qf[kk], sacc[c], 0, 0, 0);

        // scale to log2 domain + causal mask (diag tile only) + in-lane max
        float sv[4][4];
        const bool diag = (kt == qblk);
        float mt = -INFINITY;
#pragma unroll
        for (int c = 0; c < 4; ++c)
#pragma unroll
            for (int r = 0; r < 4; ++r) {
                float val = sacc[c][r] * kscale;
                if (diag && (c * 16 + quad * 4 + r > qloc)) val = -INFINITY;
                sv[c][r] = val;
                mt = fmaxf(mt, val);
            }
        mt = fmaxf(mt, __shfl_xor(mt, 16));
        mt = fmaxf(mt, __shfl_xor(mt, 32));
        const float mnew = fmaxf(mrun, mt);

        float lad = 0.f;
#pragma unroll
        for (int c = 0; c < 4; ++c)
#pragma unroll
            for (int r = 0; r < 4; ++r) {
                const float pv = exp2f(sv[c][r] - mnew);
                sv[c][r] = pv;
                lad += pv;
            }

        // P: pack 4 consecutive keys -> ds_write_b64 into Pl[q][key] (per-wave)
#pragma unroll
        for (int c = 0; c < 4; ++c) {
            bf16x4 pk = {(__bf16)sv[c][0], (__bf16)sv[c][1], (__bf16)sv[c][2], (__bf16)sv[c][3]};
            *(bf16x4*)&Pl[wv][col][c * 16 + quad * 4] = pk;
        }

        // conditional O-rescale (skip when no lane's running max moved)
        if (__ballot(mnew > mrun) != 0ull) {
            const float alpha = exp2f(mrun - mnew);
            float ar[4];
#pragma unroll
            for (int r = 0; r < 4; ++r) ar[r] = __shfl(alpha, quad * 20 + r);
#pragma unroll
            for (int dt = 0; dt < 8; ++dt)
#pragma unroll
                for (int r = 0; r < 4; ++r) oacc[dt][r] *= ar[r];
            lrun = lrun * alpha + lad;
        } else {
            lrun += lad;
        }
        mrun = mnew;

        // O += P(16x64) @ V(64x128), V B-frags direct from global vT rows
#pragma unroll
        for (int ks = 0; ks < 2; ++ks) {
            bf16x8 vf[8];
#pragma unroll
            for (int dt = 0; dt < 8; ++dt)
                vf[dt] = *(const bf16x8*)(vLane + (size_t)(dt * 16) * S + kt64 + ks * 32);
            bf16x8 af = *(const bf16x8*)&Pl[wv][col][ks * 32 + quad * 8];
#pragma unroll
            for (int dt = 0; dt < 8; ++dt)
                oacc[dt] = __builtin_amdgcn_mfma_f32_16x16x32_bf16(af, vf[dt], oacc[dt], 0, 0, 0);
        }
    }

    // epilogue: cross-quad l reduce, shuffle to O rows, store
    float l = lrun;
    l += __shfl_xor(l, 16);
    l += __shfl_xor(l, 32);
    const float linv = 1.0f / l;
    float lr[4];
#pragma unroll
    for (int r = 0; r < 4; ++r) lr[r] = __shfl(linv, quad * 20 + r);
#pragma unroll
    for (int r = 0; r < 4; ++r) {
        const int qrow = q0 + wv * 16 + quad * 4 + r;
        float* ob = out + ((size_t)h * S + qrow) * D;
#pragma unroll
        for (int dt = 0; dt < 8; ++dt)
            ob[dt * 16 + col] = oacc[dt][r] * lr[r];
    }
}

// ---------------------------------------------------------------------------
extern "C" void kernel_launch(void* const* d_in, const int* in_sizes, int n_in,
                              void* d_out, int out_size, void* d_ws, size_t ws_size,
                              hipStream_t stream) {
    const float* Q = (const float*)d_in[0];
    const float* K = (const float*)d_in[1];
    const float* V = (const float*)d_in[2];
    float* out = (float*)d_out;

    char* ws = (char*)d_ws;
    const size_t nElem = (size_t)H * S * D;                  // 8,388,608
    __bf16* k_rec = (__bf16*)ws;                             // 16.78 MB
    __bf16* vT    = (__bf16*)(ws + nElem * 2);               // 16.78 MB
    float*  cand  = (float*)(ws + nElem * 4);                // 4096*136*4 = 2.23 MB
    float2* ktab  = (float2*)(ws + nElem * 4 + (size_t)4096 * 136 * 4);          // 32 KB
    float2* vtab  = (float2*)(ws + nElem * 4 + (size_t)4096 * 136 * 4 + 32768);  // 512 KB

    stats_kernel<<<dim3(512), 256, 0, stream>>>(K, V, cand, vtab);
    kmerge_kernel<<<dim3(16), 256, 0, stream>>>(cand, ktab);
    apply_kernel<<<dim3(9216), 256, 0, stream>>>(K, V, ktab, vtab, k_rec, vT);
    attn_kernel<<<dim3(32, H), 256, 0, stream>>>(Q, k_rec, vT, out);
}

// Round 5
// 267.835 us; speedup vs baseline: 1.7589x; 1.7589x over previous
//
#include <hip/hip_runtime.h>
#include <math.h>

// B=1, H=32, S=2048, D=128, N_OUT=16, QMAX=7, EPS=1e-6
// Top-k indices never needed: only 16th (outlier threshold, kept exact) and
// 17th (scale) order statistics of |x| per slice.

typedef __bf16 bf16x8 __attribute__((ext_vector_type(8)));
typedef __bf16 bf16x4 __attribute__((ext_vector_type(4)));
typedef float f32x4 __attribute__((ext_vector_type(4)));

#define H 32
#define S 2048
#define D 128

// Branch-free descending top-17 insert: t[j] = med3(x, t[j-1], t[j]).
__device__ __forceinline__ void ins17(float t[17], float x) {
#pragma unroll
    for (int j = 16; j >= 1; --j) t[j] = __builtin_amdgcn_fmed3f(x, t[j - 1], t[j]);
    t[0] = fmaxf(t[0], x);
}

// ---------------------------------------------------------------------------
// Fused kernel 1:
//   blocks 0..255    : K partial top-17 per (h,ch) over a 256-token chunk.
//   blocks 256..1279 : V single-pass stats+apply+transpose for 64 rows.
//                      V tile staged in LDS (coalesced); all global traffic
//                      coalesced; V read exactly once.
// ---------------------------------------------------------------------------
#define VT_STRIDE 132   // 128 + 4 pad: LDS col reads are 2-way (free)

__global__ __launch_bounds__(256) void stats_kernel(const float* __restrict__ K,
                                                    const float* __restrict__ V,
                                                    float* __restrict__ cand,
                                                    __bf16* __restrict__ vT) {
    __shared__ char smem[65792] __attribute__((aligned(16)));
    if (blockIdx.x < 256) {
        float (*ml)[17] = (float (*)[17])smem;             // [128][17]
        const int h = blockIdx.x >> 3, tc = blockIdx.x & 7;
        const int ch = threadIdx.x & 127, ts = threadIdx.x >> 7;
        const float* p = K + ((size_t)h * S + tc * 256 + ts * 128) * D + ch;
        float ta[17], tb[17];
#pragma unroll
        for (int j = 0; j < 17; ++j) { ta[j] = -1.f; tb[j] = -1.f; }
#pragma unroll 8
        for (int i = 0; i < 64; ++i) {
            ins17(ta, fabsf(p[(size_t)i * D]));
            ins17(tb, fabsf(p[(size_t)(i + 64) * D]));
        }
#pragma unroll
        for (int j = 0; j < 17; ++j) ins17(ta, tb[j]);
        if (ts == 1) {
#pragma unroll
            for (int j = 0; j < 17; ++j) ml[ch][j] = ta[j];
        }
        __syncthreads();
        if (ts == 0) {
#pragma unroll
            for (int j = 0; j < 17; ++j) ins17(ta, ml[ch][j]);
            float* o = cand + ((size_t)(h * 128 + ch) * 8 + tc) * 17;
#pragma unroll
            for (int j = 0; j < 17; ++j) o[j] = ta[j];
        }
    } else {
        float (*vtile)[VT_STRIDE] = (float (*)[VT_STRIDE])smem;            // [64][132] 33792B
        float (*mlist)[3][17] = (float (*)[3][17])(smem + 33792);          // [64][3][17] 13056B
        float2* thrsc = (float2*)(smem + 46848);                           // [64] 512B
        __bf16 (*otile)[72] = (__bf16 (*)[72])(smem + 47360);              // [128][72] 18432B

        const int lin = blockIdx.x - 256;
        const int h = lin >> 5;
        const int s0 = (lin & 31) * 64;
        const int tid = threadIdx.x;

        // phase 1: coalesced load of 64 rows x 128 ch into LDS
        const float4* gsrc = (const float4*)(V + ((size_t)h * S + s0) * D);
#pragma unroll
        for (int i = 0; i < 8; ++i) {
            const int idx = i * 256 + tid;             // float4 index, 2048 total
            const int row = idx >> 5, col4 = idx & 31;
            *(float4*)&vtile[row][col4 * 4] = gsrc[idx];
        }
        __syncthreads();

        // phase 2: per-row top-17; 4 threads/row x 32 channels, LDS merge
        const int row = tid >> 2, seg = tid & 3;
        {
            float t0[17];
#pragma unroll
            for (int j = 0; j < 17; ++j) t0[j] = -1.f;
#pragma unroll 8
            for (int c = 0; c < 32; ++c) ins17(t0, fabsf(vtile[row][seg * 32 + c]));
            if (seg != 0) {
#pragma unroll
                for (int j = 0; j < 17; ++j) mlist[row][seg - 1][j] = t0[j];
            }
            __syncthreads();
            if (seg == 0) {
#pragma unroll
                for (int s = 0; s < 3; ++s)
#pragma unroll
                    for (int j = 0; j < 17; ++j) ins17(t0, mlist[row][s][j]);
                thrsc[row] = make_float2(t0[15], fmaxf(t0[16], 1e-6f) / 7.0f);
            }
            __syncthreads();
        }

        // phase 3: apply + transpose (vtile -> bf16 otile[ch][s])
        const int wv = tid >> 6, lane = tid & 63;
#pragma unroll
        for (int g = 0; g < 2; ++g) {
            bf16x8 b0, b1;
#pragma unroll
            for (int it = 0; it < 8; ++it) {
                const int srel = wv * 16 + g * 8 + it;
                const float2 tc = thrsc[srel];
                const float a = vtile[srel][lane], b = vtile[srel][lane + 64];
                float o0, o1;
                if (fabsf(a) >= tc.x) o0 = a;
                else { float q = rintf(a / tc.y); q = fminf(fmaxf(q, -7.f), 7.f); o0 = q * tc.y; }
                if (fabsf(b) >= tc.x) o1 = b;
                else { float q = rintf(b / tc.y); q = fminf(fmaxf(q, -7.f), 7.f); o1 = q * tc.y; }
                b0[it] = (__bf16)o0;
                b1[it] = (__bf16)o1;
            }
            *(bf16x8*)&otile[lane][wv * 16 + g * 8] = b0;
            *(bf16x8*)&otile[lane + 64][wv * 16 + g * 8] = b1;
        }
        __syncthreads();
        const int dRow = tid >> 3, c3 = tid & 7;
#pragma unroll
        for (int i = 0; i < 4; ++i) {
            const int d = dRow + 32 * i;
            bf16x8 val = *(const bf16x8*)&otile[d][c3 * 8];
            *(bf16x8*)&vT[((size_t)h * D + d) * S + s0 + c3 * 8] = val;
        }
    }
}

// ---------------------------------------------------------------------------
// K stats phase 2: merge 8 partial lists (136 floats) -> thr16 + scale.
// ---------------------------------------------------------------------------
__global__ __launch_bounds__(256) void kmerge_kernel(const float* __restrict__ cand,
                                                     float2* __restrict__ ktab) {
    const int g = blockIdx.x * 256 + threadIdx.x;      // (h*128+ch), 4096 total
    const float* p = cand + (size_t)g * 136;
    float t0[17], t1[17], t2[17], t3[17];
#pragma unroll
    for (int j = 0; j < 17; ++j) { t0[j] = -1.f; t1[j] = -1.f; t2[j] = -1.f; t3[j] = -1.f; }
#pragma unroll 2
    for (int i = 0; i < 34; ++i) {
        ins17(t0, p[i]);
        ins17(t1, p[34 + i]);
        ins17(t2, p[68 + i]);
        ins17(t3, p[102 + i]);
    }
#pragma unroll
    for (int j = 0; j < 17; ++j) { ins17(t0, t1[j]); ins17(t2, t3[j]); }
#pragma unroll
    for (int j = 0; j < 17; ++j) ins17(t0, t2[j]);
    ktab[g] = make_float2(t0[15], fmaxf(t0[16], 1e-6f) / 7.0f);
}

// ---------------------------------------------------------------------------
// K apply: elementwise fake-quant, fully coalesced.
// ---------------------------------------------------------------------------
__global__ __launch_bounds__(256) void kapply_kernel(const float* __restrict__ K,
                                                     const float2* __restrict__ ktab,
                                                     __bf16* __restrict__ k_rec) {
    const size_t base = ((size_t)blockIdx.x * 256 + threadIdx.x) * 4;
    const int h = (int)(base >> 18);            // S*D = 2^18
    const int d0 = (int)(base & (D - 1));
    const float4 x = *(const float4*)(K + base);
    const float2* tp = ktab + h * D + d0;
    float xs[4] = {x.x, x.y, x.z, x.w};
    bf16x4 o;
#pragma unroll
    for (int c = 0; c < 4; ++c) {
        const float2 tc = tp[c];
        float v;
        if (fabsf(xs[c]) >= tc.x) v = xs[c];
        else {
            float q = rintf(xs[c] / tc.y);
            q = fminf(fmaxf(q, -7.f), 7.f);
            v = q * tc.y;
        }
        o[c] = (__bf16)v;
    }
    *(bf16x4*)(k_rec + base) = o;
}

// ---------------------------------------------------------------------------
// Causal flash attention: r2's paired grid + LDS staging + reg prefetch,
// r3's S^T in-lane softmax, r4's conditional rescale.
// Block = 4 waves = 64 q-rows; pair (i, 31-i) -> uniform 33 tiles/block.
// ---------------------------------------------------------------------------
__global__ __launch_bounds__(256, 3) void attn_kernel(const float* __restrict__ Q,
                                                      const __bf16* __restrict__ k_rec,
                                                      const __bf16* __restrict__ vT,
                                                      float* __restrict__ out) {
    __shared__ __bf16 Kl[64][136];
    __shared__ __bf16 Vt[128][72];
    __shared__ __bf16 Pl[4][16][72];

    const int h = blockIdx.y;
    const int tid = threadIdx.x;
    const int wv = tid >> 6;
    const int lane = tid & 63;
    const int quad = lane >> 4;
    const int col = lane & 15;
    const int rowq16 = tid >> 4, chunk = tid & 15;   // K staging
    const int dRow = tid >> 3, c3 = tid & 7;         // V staging
    const __bf16* kb = k_rec + (size_t)h * S * D;
    const __bf16* vb = vT + (size_t)h * D * S;
    const float kscale = 0.08838834764831845f * 1.4426950408889634f;  // 1/sqrt(D)*log2e

#pragma unroll 1
    for (int phase = 0; phase < 2; ++phase) {
        const int qblk = (phase == 0) ? blockIdx.x : 31 - blockIdx.x;
        const int q0 = qblk * 64;
        const int qloc = wv * 16 + col;

        // Q fragments (B-operand: n=col=q, k=quad*8+j), fp32->bf16 once
        bf16x8 qf[4];
        {
            const float* qbase = Q + ((size_t)h * S + q0 + wv * 16 + col) * D + quad * 8;
#pragma unroll
            for (int kk = 0; kk < 4; ++kk) {
                const float4 a = *(const float4*)(qbase + kk * 32);
                const float4 b = *(const float4*)(qbase + kk * 32 + 4);
                qf[kk] = (bf16x8){(__bf16)a.x, (__bf16)a.y, (__bf16)a.z, (__bf16)a.w,
                                  (__bf16)b.x, (__bf16)b.y, (__bf16)b.z, (__bf16)b.w};
            }
        }

        f32x4 oacc[8];
#pragma unroll
        for (int dt = 0; dt < 8; ++dt) oacc[dt] = (f32x4){0.f, 0.f, 0.f, 0.f};
        float mrun = -INFINITY;
        float lrun = 0.f;

        // prefetch tile 0 into registers
        bf16x8 kreg[4], vreg[4];
#pragma unroll
        for (int i = 0; i < 4; ++i) {
            kreg[i] = *(const bf16x8*)&kb[(size_t)(rowq16 + 16 * i) * D + chunk * 8];
            vreg[i] = *(const bf16x8*)&vb[(size_t)(dRow + 32 * i) * S + c3 * 8];
        }

        for (int kt = 0; kt <= qblk; ++kt) {
            __syncthreads();                      // prior tile's readers done
#pragma unroll
            for (int i = 0; i < 4; ++i) {
                *(bf16x8*)&Kl[rowq16 + 16 * i][chunk * 8] = kreg[i];
                *(bf16x8*)&Vt[dRow + 32 * i][c3 * 8] = vreg[i];
            }
            if (kt < qblk) {                      // prefetch next tile
                const int kn = kt + 1;
#pragma unroll
                for (int i = 0; i < 4; ++i) {
                    kreg[i] = *(const bf16x8*)&kb[(size_t)(kn * 64 + rowq16 + 16 * i) * D + chunk * 8];
                    vreg[i] = *(const bf16x8*)&vb[(size_t)(dRow + 32 * i) * S + kn * 64 + c3 * 8];
                }
            }
            __syncthreads();                      // LDS tiles visible

            // S^T = K_tile(64x128) @ Q^T(128x16): A = K rows (m=key), B = Q (n=q)
            f32x4 sacc[4];
#pragma unroll
            for (int c = 0; c < 4; ++c) sacc[c] = (f32x4){0.f, 0.f, 0.f, 0.f};
#pragma unroll
            for (int kk = 0; kk < 4; ++kk)
#pragma unroll
                for (int c = 0; c < 4; ++c) {
                    bf16x8 kfrag = *(const bf16x8*)&Kl[c * 16 + col][kk * 32 + quad * 8];
                    sacc[c] = __builtin_amdgcn_mfma_f32_16x16x32_bf16(kfrag, qf[kk], sacc[c], 0, 0, 0);
                }

            // scale to log2 domain + causal mask (diag tile only) + in-lane max
            float sv[4][4];
            const bool diag = (kt == qblk);
            float mt = -INFINITY;
#pragma unroll
            for (int c = 0; c < 4; ++c)
#pragma unroll
                for (int r = 0; r < 4; ++r) {
                    float val = sacc[c][r] * kscale;
                    if (diag && (c * 16 + quad * 4 + r > qloc)) val = -INFINITY;
                    sv[c][r] = val;
                    mt = fmaxf(mt, val);
                }
            mt = fmaxf(mt, __shfl_xor(mt, 16));
            mt = fmaxf(mt, __shfl_xor(mt, 32));
            const float mnew = fmaxf(mrun, mt);

            float lad = 0.f;
#pragma unroll
            for (int c = 0; c < 4; ++c)
#pragma unroll
                for (int r = 0; r < 4; ++r) {
                    const float pv = exp2f(sv[c][r] - mnew);
                    sv[c][r] = pv;
                    lad += pv;
                }

            // P: pack 4 consecutive keys -> ds_write_b64 into Pl[q][key] (per-wave)
#pragma unroll
            for (int c = 0; c < 4; ++c) {
                bf16x4 pk = {(__bf16)sv[c][0], (__bf16)sv[c][1], (__bf16)sv[c][2], (__bf16)sv[c][3]};
                *(bf16x4*)&Pl[wv][col][c * 16 + quad * 4] = pk;
            }

            // conditional O-rescale (skip when no lane's running max moved)
            if (__ballot(mnew > mrun) != 0ull) {
                const float alpha = exp2f(mrun - mnew);
                float ar[4];
#pragma unroll
                for (int r = 0; r < 4; ++r) ar[r] = __shfl(alpha, quad * 20 + r);
#pragma unroll
                for (int dt = 0; dt < 8; ++dt)
#pragma unroll
                    for (int r = 0; r < 4; ++r) oacc[dt][r] *= ar[r];
                lrun = lrun * alpha + lad;
            } else {
                lrun += lad;
            }
            mrun = mnew;

            // O += P(16x64) @ V(64x128)
#pragma unroll
            for (int ks = 0; ks < 2; ++ks) {
                bf16x8 af = *(const bf16x8*)&Pl[wv][col][ks * 32 + quad * 8];
#pragma unroll
                for (int dt = 0; dt < 8; ++dt) {
                    bf16x8 bfrag = *(const bf16x8*)&Vt[dt * 16 + col][ks * 32 + quad * 8];
                    oacc[dt] = __builtin_amdgcn_mfma_f32_16x16x32_bf16(af, bfrag, oacc[dt], 0, 0, 0);
                }
            }
        }

        // epilogue: cross-quad l reduce, shuffle to O rows, store
        float l = lrun;
        l += __shfl_xor(l, 16);
        l += __shfl_xor(l, 32);
        const float linv = 1.0f / l;
        float lr[4];
#pragma unroll
        for (int r = 0; r < 4; ++r) lr[r] = __shfl(linv, quad * 20 + r);
#pragma unroll
        for (int r = 0; r < 4; ++r) {
            const int qrow = q0 + wv * 16 + quad * 4 + r;
            float* ob = out + ((size_t)h * S + qrow) * D;
#pragma unroll
            for (int dt = 0; dt < 8; ++dt)
                ob[dt * 16 + col] = oacc[dt][r] * lr[r];
        }
    }
}

// ---------------------------------------------------------------------------
extern "C" void kernel_launch(void* const* d_in, const int* in_sizes, int n_in,
                              void* d_out, int out_size, void* d_ws, size_t ws_size,
                              hipStream_t stream) {
    const float* Q = (const float*)d_in[0];
    const float* K = (const float*)d_in[1];
    const float* V = (const float*)d_in[2];
    float* out = (float*)d_out;

    char* ws = (char*)d_ws;
    const size_t nElem = (size_t)H * S * D;                  // 8,388,608
    __bf16* k_rec = (__bf16*)ws;                             // 16.78 MB
    __bf16* vT    = (__bf16*)(ws + nElem * 2);               // 16.78 MB
    float*  cand  = (float*)(ws + nElem * 4);                // 4096*136*4 = 2.23 MB
    float2* ktab  = (float2*)(ws + nElem * 4 + (size_t)4096 * 136 * 4);   // 32 KB

    stats_kernel<<<dim3(1280), 256, 0, stream>>>(K, V, cand, vT);
    kmerge_kernel<<<dim3(16), 256, 0, stream>>>(cand, ktab);
    kapply_kernel<<<dim3(nElem / 1024), 256, 0, stream>>>(K, ktab, k_rec);
    attn_kernel<<<dim3(16, H), 256, 0, stream>>>(Q, k_rec, vT, out);
}

// Round 6
// 250.873 us; speedup vs baseline: 1.8779x; 1.0676x over previous
//
#include <hip/hip_runtime.h>
#include <math.h>

// B=1, H=32, S=2048, D=128, N_OUT=16, QMAX=7, EPS=1e-6
// Top-k indices never needed: only 16th (outlier threshold, kept exact) and
// 17th (scale) order statistics of |x| per slice.

typedef __bf16 bf16x8 __attribute__((ext_vector_type(8)));
typedef __bf16 bf16x4 __attribute__((ext_vector_type(4)));
typedef float f32x4 __attribute__((ext_vector_type(4)));

#define H 32
#define S 2048
#define D 128

// Branch-free descending top-17 insert: t[j] = med3(x, t[j-1], t[j]).
__device__ __forceinline__ void ins17(float t[17], float x) {
#pragma unroll
    for (int j = 16; j >= 1; --j) t[j] = __builtin_amdgcn_fmed3f(x, t[j - 1], t[j]);
    t[0] = fmaxf(t[0], x);
}

// ---------------------------------------------------------------------------
// Fused kernel 1:
//   blocks 0..255    : K partial top-17 per (h,ch) over a 256-token chunk.
//   blocks 256..1279 : V single-pass stats+apply+transpose for 64 rows.
// ---------------------------------------------------------------------------
#define VT_STRIDE 132   // 128 + 4 pad: LDS col reads are 2-way (free)

__global__ __launch_bounds__(256) void stats_kernel(const float* __restrict__ K,
                                                    const float* __restrict__ V,
                                                    float* __restrict__ cand,
                                                    __bf16* __restrict__ vT) {
    __shared__ char smem[65792] __attribute__((aligned(16)));
    if (blockIdx.x < 256) {
        float (*ml)[17] = (float (*)[17])smem;             // [128][17]
        const int h = blockIdx.x >> 3, tc = blockIdx.x & 7;
        const int ch = threadIdx.x & 127, ts = threadIdx.x >> 7;
        const float* p = K + ((size_t)h * S + tc * 256 + ts * 128) * D + ch;
        float ta[17], tb[17];
#pragma unroll
        for (int j = 0; j < 17; ++j) { ta[j] = -1.f; tb[j] = -1.f; }
#pragma unroll 8
        for (int i = 0; i < 64; ++i) {
            ins17(ta, fabsf(p[(size_t)i * D]));
            ins17(tb, fabsf(p[(size_t)(i + 64) * D]));
        }
#pragma unroll
        for (int j = 0; j < 17; ++j) ins17(ta, tb[j]);
        if (ts == 1) {
#pragma unroll
            for (int j = 0; j < 17; ++j) ml[ch][j] = ta[j];
        }
        __syncthreads();
        if (ts == 0) {
#pragma unroll
            for (int j = 0; j < 17; ++j) ins17(ta, ml[ch][j]);
            float* o = cand + ((size_t)(h * 128 + ch) * 8 + tc) * 17;
#pragma unroll
            for (int j = 0; j < 17; ++j) o[j] = ta[j];
        }
    } else {
        float (*vtile)[VT_STRIDE] = (float (*)[VT_STRIDE])smem;            // [64][132]
        float (*mlist)[3][17] = (float (*)[3][17])(smem + 33792);          // [64][3][17]
        float2* thrsc = (float2*)(smem + 46848);                           // [64]
        __bf16 (*otile)[72] = (__bf16 (*)[72])(smem + 47360);              // [128][72]

        const int lin = blockIdx.x - 256;
        const int h = lin >> 5;
        const int s0 = (lin & 31) * 64;
        const int tid = threadIdx.x;

        // phase 1: coalesced load of 64 rows x 128 ch into LDS
        const float4* gsrc = (const float4*)(V + ((size_t)h * S + s0) * D);
#pragma unroll
        for (int i = 0; i < 8; ++i) {
            const int idx = i * 256 + tid;
            const int row = idx >> 5, col4 = idx & 31;
            *(float4*)&vtile[row][col4 * 4] = gsrc[idx];
        }
        __syncthreads();

        // phase 2: per-row top-17; 4 threads/row x 32 channels, LDS merge
        const int row = tid >> 2, seg = tid & 3;
        {
            float t0[17];
#pragma unroll
            for (int j = 0; j < 17; ++j) t0[j] = -1.f;
#pragma unroll 8
            for (int c = 0; c < 32; ++c) ins17(t0, fabsf(vtile[row][seg * 32 + c]));
            if (seg != 0) {
#pragma unroll
                for (int j = 0; j < 17; ++j) mlist[row][seg - 1][j] = t0[j];
            }
            __syncthreads();
            if (seg == 0) {
#pragma unroll
                for (int s = 0; s < 3; ++s)
#pragma unroll
                    for (int j = 0; j < 17; ++j) ins17(t0, mlist[row][s][j]);
                thrsc[row] = make_float2(t0[15], fmaxf(t0[16], 1e-6f) / 7.0f);
            }
            __syncthreads();
        }

        // phase 3: apply + transpose (vtile -> bf16 otile[ch][s])
        const int wv = tid >> 6, lane = tid & 63;
#pragma unroll
        for (int g = 0; g < 2; ++g) {
            bf16x8 b0, b1;
#pragma unroll
            for (int it = 0; it < 8; ++it) {
                const int srel = wv * 16 + g * 8 + it;
                const float2 tc = thrsc[srel];
                const float a = vtile[srel][lane], b = vtile[srel][lane + 64];
                float o0, o1;
                if (fabsf(a) >= tc.x) o0 = a;
                else { float q = rintf(a / tc.y); q = fminf(fmaxf(q, -7.f), 7.f); o0 = q * tc.y; }
                if (fabsf(b) >= tc.x) o1 = b;
                else { float q = rintf(b / tc.y); q = fminf(fmaxf(q, -7.f), 7.f); o1 = q * tc.y; }
                b0[it] = (__bf16)o0;
                b1[it] = (__bf16)o1;
            }
            *(bf16x8*)&otile[lane][wv * 16 + g * 8] = b0;
            *(bf16x8*)&otile[lane + 64][wv * 16 + g * 8] = b1;
        }
        __syncthreads();
        const int dRow = tid >> 3, c3 = tid & 7;
#pragma unroll
        for (int i = 0; i < 4; ++i) {
            const int d = dRow + 32 * i;
            bf16x8 val = *(const bf16x8*)&otile[d][c3 * 8];
            *(bf16x8*)&vT[((size_t)h * D + d) * S + s0 + c3 * 8] = val;
        }
    }
}

// ---------------------------------------------------------------------------
// K stats phase 2: merge 8 partial lists (136 floats) -> thr16 + scale.
// ---------------------------------------------------------------------------
__global__ __launch_bounds__(256) void kmerge_kernel(const float* __restrict__ cand,
                                                     float2* __restrict__ ktab) {
    const int g = blockIdx.x * 256 + threadIdx.x;      // (h*128+ch), 4096 total
    const float* p = cand + (size_t)g * 136;
    float t0[17], t1[17], t2[17], t3[17];
#pragma unroll
    for (int j = 0; j < 17; ++j) { t0[j] = -1.f; t1[j] = -1.f; t2[j] = -1.f; t3[j] = -1.f; }
#pragma unroll 2
    for (int i = 0; i < 34; ++i) {
        ins17(t0, p[i]);
        ins17(t1, p[34 + i]);
        ins17(t2, p[68 + i]);
        ins17(t3, p[102 + i]);
    }
#pragma unroll
    for (int j = 0; j < 17; ++j) { ins17(t0, t1[j]); ins17(t2, t3[j]); }
#pragma unroll
    for (int j = 0; j < 17; ++j) ins17(t0, t2[j]);
    ktab[g] = make_float2(t0[15], fmaxf(t0[16], 1e-6f) / 7.0f);
}

// ---------------------------------------------------------------------------
// K apply: elementwise fake-quant, fully coalesced.
// ---------------------------------------------------------------------------
__global__ __launch_bounds__(256) void kapply_kernel(const float* __restrict__ K,
                                                     const float2* __restrict__ ktab,
                                                     __bf16* __restrict__ k_rec) {
    const size_t base = ((size_t)blockIdx.x * 256 + threadIdx.x) * 4;
    const int h = (int)(base >> 18);            // S*D = 2^18
    const int d0 = (int)(base & (D - 1));
    const float4 x = *(const float4*)(K + base);
    const float2* tp = ktab + h * D + d0;
    float xs[4] = {x.x, x.y, x.z, x.w};
    bf16x4 o;
#pragma unroll
    for (int c = 0; c < 4; ++c) {
        const float2 tc = tp[c];
        float v;
        if (fabsf(xs[c]) >= tc.x) v = xs[c];
        else {
            float q = rintf(xs[c] / tc.y);
            q = fminf(fmaxf(q, -7.f), 7.f);
            v = q * tc.y;
        }
        o[c] = (__bf16)v;
    }
    *(bf16x4*)(k_rec + base) = o;
}

// ---------------------------------------------------------------------------
// Causal flash attention, S^T form, LDS staging + reg prefetch.
// Grid: 1024 linear blocks. h = (id&7) + 8*((id>>3)&3) pins each head's 32
// blocks to one XCD (4 heads x 1MB KV = 4MB = XCD L2); qblk = 31-(id>>5)
// makes co-resident block sizes mixed & heavy-first (r3 failure = correlated
// sizes, not unpairing). Softmax: Q pre-scaled by 1/sqrt(D)*log2e; threshold-
// rebase (only when tile max exceeds base+8) -> rescale is rare.
// ---------------------------------------------------------------------------
__global__ __launch_bounds__(256, 3) void attn_kernel(const float* __restrict__ Q,
                                                      const __bf16* __restrict__ k_rec,
                                                      const __bf16* __restrict__ vT,
                                                      float* __restrict__ out) {
    __shared__ __bf16 Kl[64][136];
    __shared__ __bf16 Vt[128][72];
    __shared__ __bf16 Pl[4][16][72];

    const int id = blockIdx.x;
    const int h = (id & 7) + 8 * ((id >> 3) & 3);
    const int qblk = 31 - (id >> 5);
    const int tid = threadIdx.x;
    const int wv = tid >> 6;
    const int lane = tid & 63;
    const int quad = lane >> 4;
    const int col = lane & 15;
    const int rowq16 = tid >> 4, chunk = tid & 15;   // K staging
    const int dRow = tid >> 3, c3 = tid & 7;         // V staging
    const __bf16* kb = k_rec + (size_t)h * S * D;
    const __bf16* vb = vT + (size_t)h * D * S;
    const float kscale = 0.08838834764831845f * 1.4426950408889634f;  // 1/sqrt(D)*log2e
    const int q0 = qblk * 64;
    const int qloc = wv * 16 + col;

    // Q fragments (B-operand: n=col=q, k=quad*8+j), fp32 -> scale -> bf16
    bf16x8 qf[4];
    {
        const float* qbase = Q + ((size_t)h * S + q0 + wv * 16 + col) * D + quad * 8;
#pragma unroll
        for (int kk = 0; kk < 4; ++kk) {
            const float4 a = *(const float4*)(qbase + kk * 32);
            const float4 b = *(const float4*)(qbase + kk * 32 + 4);
            qf[kk] = (bf16x8){(__bf16)(a.x * kscale), (__bf16)(a.y * kscale),
                              (__bf16)(a.z * kscale), (__bf16)(a.w * kscale),
                              (__bf16)(b.x * kscale), (__bf16)(b.y * kscale),
                              (__bf16)(b.z * kscale), (__bf16)(b.w * kscale)};
        }
    }

    f32x4 oacc[8];
#pragma unroll
    for (int dt = 0; dt < 8; ++dt) oacc[dt] = (f32x4){0.f, 0.f, 0.f, 0.f};
    f32x4 lsum = (f32x4){0.f, 0.f, 0.f, 0.f};
    float mbase = -INFINITY;                 // normalization base (rebased rarely)

    // prefetch tile 0 into registers
    bf16x8 kreg[4], vreg[4];
#pragma unroll
    for (int i = 0; i < 4; ++i) {
        kreg[i] = *(const bf16x8*)&kb[(size_t)(rowq16 + 16 * i) * D + chunk * 8];
        vreg[i] = *(const bf16x8*)&vb[(size_t)(dRow + 32 * i) * S + c3 * 8];
    }

    for (int kt = 0; kt <= qblk; ++kt) {
        __syncthreads();                      // prior tile's readers done
#pragma unroll
        for (int i = 0; i < 4; ++i) {
            *(bf16x8*)&Kl[rowq16 + 16 * i][chunk * 8] = kreg[i];
            *(bf16x8*)&Vt[dRow + 32 * i][c3 * 8] = vreg[i];
        }
        if (kt < qblk) {                      // prefetch next tile
            const int kn = kt + 1;
#pragma unroll
            for (int i = 0; i < 4; ++i) {
                kreg[i] = *(const bf16x8*)&kb[(size_t)(kn * 64 + rowq16 + 16 * i) * D + chunk * 8];
                vreg[i] = *(const bf16x8*)&vb[(size_t)(dRow + 32 * i) * S + kn * 64 + c3 * 8];
            }
        }
        __syncthreads();                      // LDS tiles visible

        // S^T = K_tile(64x128) @ Q^T(128x16), already in log2 domain
        f32x4 sacc[4];
#pragma unroll
        for (int c = 0; c < 4; ++c) sacc[c] = (f32x4){0.f, 0.f, 0.f, 0.f};
#pragma unroll
        for (int kk = 0; kk < 4; ++kk)
#pragma unroll
            for (int c = 0; c < 4; ++c) {
                bf16x8 kfrag = *(const bf16x8*)&Kl[c * 16 + col][kk * 32 + quad * 8];
                sacc[c] = __builtin_amdgcn_mfma_f32_16x16x32_bf16(kfrag, qf[kk], sacc[c], 0, 0, 0);
            }

        // causal mask (diag tile only) + in-lane max
        float sv[4][4];
        float mt = -INFINITY;
        if (kt == qblk) {
#pragma unroll
            for (int c = 0; c < 4; ++c)
#pragma unroll
                for (int r = 0; r < 4; ++r) {
                    float val = sacc[c][r];
                    if (c * 16 + quad * 4 + r > qloc) val = -INFINITY;
                    sv[c][r] = val;
                    mt = fmaxf(mt, val);
                }
        } else {
#pragma unroll
            for (int c = 0; c < 4; ++c)
#pragma unroll
                for (int r = 0; r < 4; ++r) {
                    sv[c][r] = sacc[c][r];
                    mt = fmaxf(mt, sacc[c][r]);
                }
        }
        mt = fmaxf(mt, __shfl_xor(mt, 16));
        mt = fmaxf(mt, __shfl_xor(mt, 32));

        // threshold rebase: only when tile max exceeds base by >8 (rare)
        if (__ballot(mt > mbase + 8.f) != 0ull) {
            const float mnew = fmaxf(mbase, mt);
            const float alpha = exp2f(mbase - mnew);   // 1 for lanes not moving
            mbase = mnew;
            lsum *= alpha;
            float ar[4];
#pragma unroll
            for (int r = 0; r < 4; ++r) ar[r] = __shfl(alpha, quad * 20 + r);
#pragma unroll
            for (int dt = 0; dt < 8; ++dt)
#pragma unroll
                for (int r = 0; r < 4; ++r) oacc[dt][r] *= ar[r];
        }

        // exponentials + partial l sums (4 independent accumulators)
#pragma unroll
        for (int c = 0; c < 4; ++c) {
            float ls = lsum[c];
#pragma unroll
            for (int r = 0; r < 4; ++r) {
                const float pv = exp2f(sv[c][r] - mbase);
                sv[c][r] = pv;
                ls += pv;
            }
            lsum[c] = ls;
        }

        // P: pack 4 consecutive keys -> ds_write_b64 into Pl[q][key] (per-wave)
#pragma unroll
        for (int c = 0; c < 4; ++c) {
            bf16x4 pk = {(__bf16)sv[c][0], (__bf16)sv[c][1], (__bf16)sv[c][2], (__bf16)sv[c][3]};
            *(bf16x4*)&Pl[wv][col][c * 16 + quad * 4] = pk;
        }

        // O += P(16x64) @ V(64x128)
#pragma unroll
        for (int ks = 0; ks < 2; ++ks) {
            bf16x8 af = *(const bf16x8*)&Pl[wv][col][ks * 32 + quad * 8];
#pragma unroll
            for (int dt = 0; dt < 8; ++dt) {
                bf16x8 bfrag = *(const bf16x8*)&Vt[dt * 16 + col][ks * 32 + quad * 8];
                oacc[dt] = __builtin_amdgcn_mfma_f32_16x16x32_bf16(af, bfrag, oacc[dt], 0, 0, 0);
            }
        }
    }

    // epilogue: fold partial l, cross-quad reduce, shuffle to O rows, store
    float l = (lsum[0] + lsum[1]) + (lsum[2] + lsum[3]);
    l += __shfl_xor(l, 16);
    l += __shfl_xor(l, 32);
    const float linv = 1.0f / l;
    float lr[4];
#pragma unroll
    for (int r = 0; r < 4; ++r) lr[r] = __shfl(linv, quad * 20 + r);
#pragma unroll
    for (int r = 0; r < 4; ++r) {
        const int qrow = q0 + wv * 16 + quad * 4 + r;
        float* ob = out + ((size_t)h * S + qrow) * D;
#pragma unroll
        for (int dt = 0; dt < 8; ++dt)
            ob[dt * 16 + col] = oacc[dt][r] * lr[r];
    }
}

// ---------------------------------------------------------------------------
extern "C" void kernel_launch(void* const* d_in, const int* in_sizes, int n_in,
                              void* d_out, int out_size, void* d_ws, size_t ws_size,
                              hipStream_t stream) {
    const float* Q = (const float*)d_in[0];
    const float* K = (const float*)d_in[1];
    const float* V = (const float*)d_in[2];
    float* out = (float*)d_out;

    char* ws = (char*)d_ws;
    const size_t nElem = (size_t)H * S * D;                  // 8,388,608
    __bf16* k_rec = (__bf16*)ws;                             // 16.78 MB
    __bf16* vT    = (__bf16*)(ws + nElem * 2);               // 16.78 MB
    float*  cand  = (float*)(ws + nElem * 4);                // 2.23 MB
    float2* ktab  = (float2*)(ws + nElem * 4 + (size_t)4096 * 136 * 4);   // 32 KB

    stats_kernel<<<dim3(1280), 256, 0, stream>>>(K, V, cand, vT);
    kmerge_kernel<<<dim3(16), 256, 0, stream>>>(cand, ktab);
    kapply_kernel<<<dim3(nElem / 1024), 256, 0, stream>>>(K, ktab, k_rec);
    attn_kernel<<<dim3(1024), 256, 0, stream>>>(Q, k_rec, vT, out);
}

// Round 7
// 249.765 us; speedup vs baseline: 1.8862x; 1.0044x over previous
//
#include <hip/hip_runtime.h>
#include <math.h>

// B=1, H=32, S=2048, D=128, N_OUT=16, QMAX=7, EPS=1e-6
// Top-k indices never needed: only 16th (outlier threshold, kept exact) and
// 17th (scale) order statistics of |x| per slice.

typedef __bf16 bf16x8 __attribute__((ext_vector_type(8)));
typedef __bf16 bf16x4 __attribute__((ext_vector_type(4)));
typedef float f32x4 __attribute__((ext_vector_type(4)));

#define H 32
#define S 2048
#define D 128

// Branch-free descending top-17 insert: t[j] = med3(x, t[j-1], t[j]).
__device__ __forceinline__ void ins17(float t[17], float x) {
#pragma unroll
    for (int j = 16; j >= 1; --j) t[j] = __builtin_amdgcn_fmed3f(x, t[j - 1], t[j]);
    t[0] = fmaxf(t[0], x);
}

// ---------------------------------------------------------------------------
// Fused kernel 1:
//   blocks 0..255    : K partial top-17 per (h,ch) over a 256-token chunk.
//   blocks 256..1279 : V single-pass stats+apply+transpose for 64 rows.
// ---------------------------------------------------------------------------
#define VT_STRIDE 132   // 128 + 4 pad: LDS col reads are 2-way (free)

__global__ __launch_bounds__(256) void stats_kernel(const float* __restrict__ K,
                                                    const float* __restrict__ V,
                                                    float* __restrict__ cand,
                                                    __bf16* __restrict__ vT) {
    __shared__ char smem[65792] __attribute__((aligned(16)));
    if (blockIdx.x < 256) {
        float (*ml)[17] = (float (*)[17])smem;             // [128][17]
        const int h = blockIdx.x >> 3, tc = blockIdx.x & 7;
        const int ch = threadIdx.x & 127, ts = threadIdx.x >> 7;
        const float* p = K + ((size_t)h * S + tc * 256 + ts * 128) * D + ch;
        float ta[17], tb[17];
#pragma unroll
        for (int j = 0; j < 17; ++j) { ta[j] = -1.f; tb[j] = -1.f; }
#pragma unroll 8
        for (int i = 0; i < 64; ++i) {
            ins17(ta, fabsf(p[(size_t)i * D]));
            ins17(tb, fabsf(p[(size_t)(i + 64) * D]));
        }
#pragma unroll
        for (int j = 0; j < 17; ++j) ins17(ta, tb[j]);
        if (ts == 1) {
#pragma unroll
            for (int j = 0; j < 17; ++j) ml[ch][j] = ta[j];
        }
        __syncthreads();
        if (ts == 0) {
#pragma unroll
            for (int j = 0; j < 17; ++j) ins17(ta, ml[ch][j]);
            float* o = cand + ((size_t)(h * 128 + ch) * 8 + tc) * 17;
#pragma unroll
            for (int j = 0; j < 17; ++j) o[j] = ta[j];
        }
    } else {
        float (*vtile)[VT_STRIDE] = (float (*)[VT_STRIDE])smem;            // [64][132]
        float (*mlist)[3][17] = (float (*)[3][17])(smem + 33792);          // [64][3][17]
        float2* thrsc = (float2*)(smem + 46848);                           // [64]
        __bf16 (*otile)[72] = (__bf16 (*)[72])(smem + 47360);              // [128][72]

        const int lin = blockIdx.x - 256;
        const int h = lin >> 5;
        const int s0 = (lin & 31) * 64;
        const int tid = threadIdx.x;

        // phase 1: coalesced load of 64 rows x 128 ch into LDS
        const float4* gsrc = (const float4*)(V + ((size_t)h * S + s0) * D);
#pragma unroll
        for (int i = 0; i < 8; ++i) {
            const int idx = i * 256 + tid;
            const int row = idx >> 5, col4 = idx & 31;
            *(float4*)&vtile[row][col4 * 4] = gsrc[idx];
        }
        __syncthreads();

        // phase 2: per-row top-17; 4 threads/row x 32 channels, LDS merge
        const int row = tid >> 2, seg = tid & 3;
        {
            float t0[17];
#pragma unroll
            for (int j = 0; j < 17; ++j) t0[j] = -1.f;
#pragma unroll 8
            for (int c = 0; c < 32; ++c) ins17(t0, fabsf(vtile[row][seg * 32 + c]));
            if (seg != 0) {
#pragma unroll
                for (int j = 0; j < 17; ++j) mlist[row][seg - 1][j] = t0[j];
            }
            __syncthreads();
            if (seg == 0) {
#pragma unroll
                for (int s = 0; s < 3; ++s)
#pragma unroll
                    for (int j = 0; j < 17; ++j) ins17(t0, mlist[row][s][j]);
                thrsc[row] = make_float2(t0[15], fmaxf(t0[16], 1e-6f) / 7.0f);
            }
            __syncthreads();
        }

        // phase 3: apply + transpose (vtile -> bf16 otile[ch][s])
        const int wv = tid >> 6, lane = tid & 63;
#pragma unroll
        for (int g = 0; g < 2; ++g) {
            bf16x8 b0, b1;
#pragma unroll
            for (int it = 0; it < 8; ++it) {
                const int srel = wv * 16 + g * 8 + it;
                const float2 tc = thrsc[srel];
                const float a = vtile[srel][lane], b = vtile[srel][lane + 64];
                float o0, o1;
                if (fabsf(a) >= tc.x) o0 = a;
                else { float q = rintf(a / tc.y); q = fminf(fmaxf(q, -7.f), 7.f); o0 = q * tc.y; }
                if (fabsf(b) >= tc.x) o1 = b;
                else { float q = rintf(b / tc.y); q = fminf(fmaxf(q, -7.f), 7.f); o1 = q * tc.y; }
                b0[it] = (__bf16)o0;
                b1[it] = (__bf16)o1;
            }
            *(bf16x8*)&otile[lane][wv * 16 + g * 8] = b0;
            *(bf16x8*)&otile[lane + 64][wv * 16 + g * 8] = b1;
        }
        __syncthreads();
        const int dRow = tid >> 3, c3 = tid & 7;
#pragma unroll
        for (int i = 0; i < 4; ++i) {
            const int d = dRow + 32 * i;
            bf16x8 val = *(const bf16x8*)&otile[d][c3 * 8];
            *(bf16x8*)&vT[((size_t)h * D + d) * S + s0 + c3 * 8] = val;
        }
    }
}

// ---------------------------------------------------------------------------
// K stats phase 2: merge 8 partial lists (136 floats) -> thr16 + scale.
// ---------------------------------------------------------------------------
__global__ __launch_bounds__(256) void kmerge_kernel(const float* __restrict__ cand,
                                                     float2* __restrict__ ktab) {
    const int g = blockIdx.x * 256 + threadIdx.x;      // (h*128+ch), 4096 total
    const float* p = cand + (size_t)g * 136;
    float t0[17], t1[17], t2[17], t3[17];
#pragma unroll
    for (int j = 0; j < 17; ++j) { t0[j] = -1.f; t1[j] = -1.f; t2[j] = -1.f; t3[j] = -1.f; }
#pragma unroll 2
    for (int i = 0; i < 34; ++i) {
        ins17(t0, p[i]);
        ins17(t1, p[34 + i]);
        ins17(t2, p[68 + i]);
        ins17(t3, p[102 + i]);
    }
#pragma unroll
    for (int j = 0; j < 17; ++j) { ins17(t0, t1[j]); ins17(t2, t3[j]); }
#pragma unroll
    for (int j = 0; j < 17; ++j) ins17(t0, t2[j]);
    ktab[g] = make_float2(t0[15], fmaxf(t0[16], 1e-6f) / 7.0f);
}

// ---------------------------------------------------------------------------
// K apply: elementwise fake-quant, fully coalesced.
// ---------------------------------------------------------------------------
__global__ __launch_bounds__(256) void kapply_kernel(const float* __restrict__ K,
                                                     const float2* __restrict__ ktab,
                                                     __bf16* __restrict__ k_rec) {
    const size_t base = ((size_t)blockIdx.x * 256 + threadIdx.x) * 4;
    const int h = (int)(base >> 18);            // S*D = 2^18
    const int d0 = (int)(base & (D - 1));
    const float4 x = *(const float4*)(K + base);
    const float2* tp = ktab + h * D + d0;
    float xs[4] = {x.x, x.y, x.z, x.w};
    bf16x4 o;
#pragma unroll
    for (int c = 0; c < 4; ++c) {
        const float2 tc = tp[c];
        float v;
        if (fabsf(xs[c]) >= tc.x) v = xs[c];
        else {
            float q = rintf(xs[c] / tc.y);
            q = fminf(fmaxf(q, -7.f), 7.f);
            v = q * tc.y;
        }
        o[c] = (__bf16)v;
    }
    *(bf16x4*)(k_rec + base) = o;
}

// ---------------------------------------------------------------------------
// Causal flash attention, S^T form, LDS staging.
// KEY CHANGE (r7): next-tile global loads are issued AFTER barrier #2 (in the
// compute region). Compiler drains vmcnt(0) at every s_barrier (__syncthreads
// memory semantics), so loads issued between the barriers were drained
// immediately after issue — full L2 latency exposed per tile. Issued after
// barrier #2, they overlap the whole QK/softmax/PV compute phase and are
// drained at next iteration's barrier #1, by which point they're complete.
// Grid swizzle (r6, proven): h = (id&7)+8*((id>>3)&3) pins each head to one
// XCD; qblk = 31-(id>>5) -> sizes descending, de-correlated.
// ---------------------------------------------------------------------------
__global__ __launch_bounds__(256, 3) void attn_kernel(const float* __restrict__ Q,
                                                      const __bf16* __restrict__ k_rec,
                                                      const __bf16* __restrict__ vT,
                                                      float* __restrict__ out) {
    __shared__ __bf16 Kl[64][136];
    __shared__ __bf16 Vt[128][72];
    __shared__ __bf16 Pl[4][16][72];

    const int id = blockIdx.x;
    const int h = (id & 7) + 8 * ((id >> 3) & 3);
    const int qblk = 31 - (id >> 5);
    const int tid = threadIdx.x;
    const int wv = tid >> 6;
    const int lane = tid & 63;
    const int quad = lane >> 4;
    const int col = lane & 15;
    const int rowq16 = tid >> 4, chunk = tid & 15;   // K staging
    const int dRow = tid >> 3, c3 = tid & 7;         // V staging
    const __bf16* kb = k_rec + (size_t)h * S * D;
    const __bf16* vb = vT + (size_t)h * D * S;
    const float kscale = 0.08838834764831845f * 1.4426950408889634f;  // 1/sqrt(D)*log2e
    const int q0 = qblk * 64;
    const int qloc = wv * 16 + col;

    // Q fragments (B-operand: n=col=q, k=quad*8+j), fp32 -> scale -> bf16
    bf16x8 qf[4];
    {
        const float* qbase = Q + ((size_t)h * S + q0 + wv * 16 + col) * D + quad * 8;
#pragma unroll
        for (int kk = 0; kk < 4; ++kk) {
            const float4 a = *(const float4*)(qbase + kk * 32);
            const float4 b = *(const float4*)(qbase + kk * 32 + 4);
            qf[kk] = (bf16x8){(__bf16)(a.x * kscale), (__bf16)(a.y * kscale),
                              (__bf16)(a.z * kscale), (__bf16)(a.w * kscale),
                              (__bf16)(b.x * kscale), (__bf16)(b.y * kscale),
                              (__bf16)(b.z * kscale), (__bf16)(b.w * kscale)};
        }
    }

    f32x4 oacc[8];
#pragma unroll
    for (int dt = 0; dt < 8; ++dt) oacc[dt] = (f32x4){0.f, 0.f, 0.f, 0.f};
    f32x4 lsum = (f32x4){0.f, 0.f, 0.f, 0.f};
    float mbase = -INFINITY;                 // normalization base (rebased rarely)

    // prefetch tile 0 into registers
    bf16x8 kreg[4], vreg[4];
#pragma unroll
    for (int i = 0; i < 4; ++i) {
        kreg[i] = *(const bf16x8*)&kb[(size_t)(rowq16 + 16 * i) * D + chunk * 8];
        vreg[i] = *(const bf16x8*)&vb[(size_t)(dRow + 32 * i) * S + c3 * 8];
    }

    for (int kt = 0; kt <= qblk; ++kt) {
        __syncthreads();                      // #1: prior tile's readers done
                                              //     (also drains in-flight prefetch)
#pragma unroll
        for (int i = 0; i < 4; ++i) {
            *(bf16x8*)&Kl[rowq16 + 16 * i][chunk * 8] = kreg[i];
            *(bf16x8*)&Vt[dRow + 32 * i][c3 * 8] = vreg[i];
        }
        __syncthreads();                      // #2: LDS tiles visible (lgkm only)

        // issue next-tile prefetch NOW: overlaps the whole compute phase below
        if (kt < qblk) {
            const int kn = kt + 1;
#pragma unroll
            for (int i = 0; i < 4; ++i) {
                kreg[i] = *(const bf16x8*)&kb[(size_t)(kn * 64 + rowq16 + 16 * i) * D + chunk * 8];
                vreg[i] = *(const bf16x8*)&vb[(size_t)(dRow + 32 * i) * S + kn * 64 + c3 * 8];
            }
        }

        // S^T = K_tile(64x128) @ Q^T(128x16), already in log2 domain
        f32x4 sacc[4];
#pragma unroll
        for (int c = 0; c < 4; ++c) sacc[c] = (f32x4){0.f, 0.f, 0.f, 0.f};
#pragma unroll
        for (int kk = 0; kk < 4; ++kk)
#pragma unroll
            for (int c = 0; c < 4; ++c) {
                bf16x8 kfrag = *(const bf16x8*)&Kl[c * 16 + col][kk * 32 + quad * 8];
                sacc[c] = __builtin_amdgcn_mfma_f32_16x16x32_bf16(kfrag, qf[kk], sacc[c], 0, 0, 0);
            }

        // causal mask (diag tile only) + in-lane max
        float sv[4][4];
        float mt = -INFINITY;
        if (kt == qblk) {
#pragma unroll
            for (int c = 0; c < 4; ++c)
#pragma unroll
                for (int r = 0; r < 4; ++r) {
                    float val = sacc[c][r];
                    if (c * 16 + quad * 4 + r > qloc) val = -INFINITY;
                    sv[c][r] = val;
                    mt = fmaxf(mt, val);
                }
        } else {
#pragma unroll
            for (int c = 0; c < 4; ++c)
#pragma unroll
                for (int r = 0; r < 4; ++r) {
                    sv[c][r] = sacc[c][r];
                    mt = fmaxf(mt, sacc[c][r]);
                }
        }
        mt = fmaxf(mt, __shfl_xor(mt, 16));
        mt = fmaxf(mt, __shfl_xor(mt, 32));

        // threshold rebase: only when tile max exceeds base by >8 (rare)
        if (__ballot(mt > mbase + 8.f) != 0ull) {
            const float mnew = fmaxf(mbase, mt);
            const float alpha = exp2f(mbase - mnew);   // 1 for lanes not moving
            mbase = mnew;
            lsum *= alpha;
            float ar[4];
#pragma unroll
            for (int r = 0; r < 4; ++r) ar[r] = __shfl(alpha, quad * 20 + r);
#pragma unroll
            for (int dt = 0; dt < 8; ++dt)
#pragma unroll
                for (int r = 0; r < 4; ++r) oacc[dt][r] *= ar[r];
        }

        // exponentials + partial l sums (4 independent accumulators)
#pragma unroll
        for (int c = 0; c < 4; ++c) {
            float ls = lsum[c];
#pragma unroll
            for (int r = 0; r < 4; ++r) {
                const float pv = exp2f(sv[c][r] - mbase);
                sv[c][r] = pv;
                ls += pv;
            }
            lsum[c] = ls;
        }

        // P: pack 4 consecutive keys -> ds_write_b64 into Pl[q][key] (per-wave)
#pragma unroll
        for (int c = 0; c < 4; ++c) {
            bf16x4 pk = {(__bf16)sv[c][0], (__bf16)sv[c][1], (__bf16)sv[c][2], (__bf16)sv[c][3]};
            *(bf16x4*)&Pl[wv][col][c * 16 + quad * 4] = pk;
        }

        // O += P(16x64) @ V(64x128)
#pragma unroll
        for (int ks = 0; ks < 2; ++ks) {
            bf16x8 af = *(const bf16x8*)&Pl[wv][col][ks * 32 + quad * 8];
#pragma unroll
            for (int dt = 0; dt < 8; ++dt) {
                bf16x8 bfrag = *(const bf16x8*)&Vt[dt * 16 + col][ks * 32 + quad * 8];
                oacc[dt] = __builtin_amdgcn_mfma_f32_16x16x32_bf16(af, bfrag, oacc[dt], 0, 0, 0);
            }
        }
    }

    // epilogue: fold partial l, cross-quad reduce, shuffle to O rows, store
    float l = (lsum[0] + lsum[1]) + (lsum[2] + lsum[3]);
    l += __shfl_xor(l, 16);
    l += __shfl_xor(l, 32);
    const float linv = 1.0f / l;
    float lr[4];
#pragma unroll
    for (int r = 0; r < 4; ++r) lr[r] = __shfl(linv, quad * 20 + r);
#pragma unroll
    for (int r = 0; r < 4; ++r) {
        const int qrow = q0 + wv * 16 + quad * 4 + r;
        float* ob = out + ((size_t)h * S + qrow) * D;
#pragma unroll
        for (int dt = 0; dt < 8; ++dt)
            ob[dt * 16 + col] = oacc[dt][r] * lr[r];
    }
}

// ---------------------------------------------------------------------------
extern "C" void kernel_launch(void* const* d_in, const int* in_sizes, int n_in,
                              void* d_out, int out_size, void* d_ws, size_t ws_size,
                              hipStream_t stream) {
    const float* Q = (const float*)d_in[0];
    const float* K = (const float*)d_in[1];
    const float* V = (const float*)d_in[2];
    float* out = (float*)d_out;

    char* ws = (char*)d_ws;
    const size_t nElem = (size_t)H * S * D;                  // 8,388,608
    __bf16* k_rec = (__bf16*)ws;                             // 16.78 MB
    __bf16* vT    = (__bf16*)(ws + nElem * 2);               // 16.78 MB
    float*  cand  = (float*)(ws + nElem * 4);                // 2.23 MB
    float2* ktab  = (float2*)(ws + nElem * 4 + (size_t)4096 * 136 * 4);   // 32 KB

    stats_kernel<<<dim3(1280), 256, 0, stream>>>(K, V, cand, vT);
    kmerge_kernel<<<dim3(16), 256, 0, stream>>>(cand, ktab);
    kapply_kernel<<<dim3(nElem / 1024), 256, 0, stream>>>(K, ktab, k_rec);
    attn_kernel<<<dim3(1024), 256, 0, stream>>>(Q, k_rec, vT, out);
}